// Round 11
// baseline (1049.308 us; speedup 1.0000x reference)
//
#include <hip/hip_runtime.h>
#include <math.h>

// ---------------- problem constants ----------------
#define TDIM  100
#define HIDN  100
#define G3    300
#define WD    132
#define CIP   104      // padded ci pitch (multiple of 8)
#define KP3   2912     // fused conv K = 28*104 -> 91 ksteps of 32 (exact)
#define NKC3  91
#define GIK   17440    // padded FEAT (17424 -> 545 ksteps of 32)
#define GIN   320      // padded 3*HID
#define BTOT  16
#define INP0  (159 * WD)   // 20988
#define NPF   17424        // fused conv output positions (132*132)

typedef float    f32x4 __attribute__((ext_vector_type(4)));
typedef _Float16 f16x8 __attribute__((ext_vector_type(8)));
typedef _Float16 f16x4 __attribute__((ext_vector_type(4)));

static __device__ __forceinline__ float sigmoidf_(float x) {
    return 1.f / (1.f + __expf(-x));
}
static __device__ __forceinline__ float tanhf_(float x) {
    const float e = __expf(-2.f * fabsf(x));
    const float t = (1.f - e) / (1.f + e);
    return copysignf(t, x);
}
static __device__ __forceinline__ float bcastf(float v, int l) {
    return __int_as_float(__builtin_amdgcn_readlane(__float_as_int(v), l));
}

// async global->LDS, 16B per lane; dest = wave-uniform base + lane*16 (linear)
static __device__ __forceinline__ void gl16(const _Float16* g, _Float16* l)
{
    __builtin_amdgcn_global_load_lds(
        (const __attribute__((address_space(1))) void*)g,
        (__attribute__((address_space(3))) void*)l,
        16, 0, 0);
}

// Bijective XCD-chunked remap (m204): blocks sharing input rows -> same XCD L2.
static __device__ __forceinline__ int xcd_remap_lin()
{
    const int nwg = gridDim.x * gridDim.y * gridDim.z;
    const int lin = (blockIdx.z * gridDim.y + blockIdx.y) * gridDim.x + blockIdx.x;
    const int q = nwg >> 3, r = nwg & 7;
    const int xcd = lin & 7, idx = lin >> 3;
    return (xcd < r ? xcd * (q + 1) : r * (q + 1) + (xcd - r) * q) + idx;
}

// ---------------- conv fusion preps (3 linear convs == one 28-tap conv) -------------------
// W12[a,c,k] = sum_o sum_{k1+k2=k} W2[a,o,k2] W1[o,c,k1]   (k < 19), fp32
__global__ __launch_bounds__(256)
void prep_w12(const float* __restrict__ w1, const float* __restrict__ w2,
              float* __restrict__ w12)
{
    const int idx = blockIdx.x * 256 + threadIdx.x;
    if (idx >= 10000) return;
    const int a = idx / 100, c = idx - a * 100;
    float acc[19];
    #pragma unroll
    for (int k = 0; k < 19; ++k) acc[k] = 0.f;
    for (int b = 0; b < 100; ++b) {
        float v1[10], v2[10];
        #pragma unroll
        for (int k = 0; k < 10; ++k) v1[k] = w1[((size_t)b * 100 + c) * 10 + k];
        #pragma unroll
        for (int k = 0; k < 10; ++k) v2[k] = w2[((size_t)a * 100 + b) * 10 + k];
        #pragma unroll
        for (int k2 = 0; k2 < 10; ++k2)
            #pragma unroll
            for (int k1 = 0; k1 < 10; ++k1)
                acc[k1 + k2] += v2[k2] * v1[k1];
    }
    #pragma unroll
    for (int k = 0; k < 19; ++k) w12[(size_t)idx * 19 + k] = acc[k];
}

__global__ __launch_bounds__(256)
void zero_wp(_Float16* __restrict__ wp)
{
    const int idx = blockIdx.x * 256 + threadIdx.x;
    if (idx < 128 * KP3) wp[idx] = (_Float16)0.f;
}

// W123[o,c,k] = sum_a sum_{k12+k3=k} W3[o,a,k3] W12[a,c,k12]  (k < 28),
// packed directly as wp[o][k*104+c] fp16 (pads stay zero from zero_wp).
__global__ __launch_bounds__(256)
void prep_w123(const float* __restrict__ w12, const float* __restrict__ w3,
               _Float16* __restrict__ wp)
{
    const int idx = blockIdx.x * 256 + threadIdx.x;
    if (idx >= 10000) return;
    const int o = idx / 100, c = idx - o * 100;
    float acc[28];
    #pragma unroll
    for (int k = 0; k < 28; ++k) acc[k] = 0.f;
    for (int a = 0; a < 100; ++a) {
        float v3[10], v12[19];
        #pragma unroll
        for (int k = 0; k < 10; ++k) v3[k] = w3[((size_t)o * 100 + a) * 10 + k];
        #pragma unroll
        for (int k = 0; k < 19; ++k) v12[k] = w12[((size_t)a * 100 + c) * 19 + k];
        #pragma unroll
        for (int k3 = 0; k3 < 10; ++k3)
            #pragma unroll
            for (int k12 = 0; k12 < 19; ++k12)
                acc[k3 + k12] += v3[k3] * v12[k12];
    }
    #pragma unroll
    for (int kh = 0; kh < 28; ++kh)
        wp[(size_t)o * KP3 + kh * CIP + c] = (_Float16)acc[kh];
}

// bias123[c] = bc3[c] + sum_{a,k3} W3[c,a,k3]*(bc2[a] + sum_{o,k2} W2[a,o,k2]*bc1[o])
__global__ __launch_bounds__(128)
void prep_bias(const float* __restrict__ w2, const float* __restrict__ w3,
               const float* __restrict__ bc1, const float* __restrict__ bc2,
               const float* __restrict__ bc3, float* __restrict__ bias123)
{
    __shared__ float b12[100];
    const int tid = threadIdx.x;
    if (tid < 100) {
        float acc = bc2[tid];
        for (int o = 0; o < 100; ++o) {
            float s = 0.f;
            #pragma unroll
            for (int k = 0; k < 10; ++k) s += w2[((size_t)tid * 100 + o) * 10 + k];
            acc += s * bc1[o];
        }
        b12[tid] = acc;
    }
    __syncthreads();
    if (tid < 100) {
        float acc = bc3[tid];
        for (int a = 0; a < 100; ++a) {
            float s = 0.f;
            #pragma unroll
            for (int k = 0; k < 10; ++k) s += w3[((size_t)tid * 100 + a) * 10 + k];
            acc += s * b12[a];
        }
        bias123[tid] = acc;
    }
}

// zero gi pad columns [17424,17440) for valid rows (gemm reads them x wihp zero-pad)
__global__ __launch_bounds__(256)
void zero_gipad(_Float16* __restrict__ gi)
{
    const int idx = blockIdx.x * 256 + threadIdx.x;   // 25600
    if (idx < 1600 * 16) {
        const int row = idx >> 4, col = NPF + (idx & 15);
        gi[(size_t)row * GIK + col] = (_Float16)0.f;
    }
}

// ---------------- w_ih prepack: [300][17424] -> [GIN][GIK] fp16, zero pad ----------------
__global__ __launch_bounds__(256)
void prep_wih(const float* __restrict__ w_ih, _Float16* __restrict__ wihp)
{
    const int k = blockIdx.x * 256 + threadIdx.x;
    const int n = blockIdx.y;
    if (k >= GIK) return;
    const float v = (n < G3 && k < 17424) ? w_ih[(size_t)n * 17424 + k] : 0.f;
    wihp[(size_t)n * GIK + k] = (_Float16)v;
}

// ---------------- x transpose: x[b][ci][p] fp32 -> xT[b][p][CIP] fp16 (pad ci zeroed) -------
__global__ __launch_bounds__(256)
void transpose_x(const float* __restrict__ x, _Float16* __restrict__ xT)
{
    __shared__ __align__(16) _Float16 t[64][116];
    const int tid = threadIdx.x;
    const int p0  = blockIdx.x * 64;
    const int b   = blockIdx.y;
    const int pl  = tid & 63;
    const int p   = p0 + pl;
    t[tid >> 2][100 + (tid & 3)] = (_Float16)0.f;   // zero the ci pad (must be finite!)
    const float* xb = x + (size_t)b * 100 * INP0;
    #pragma unroll
    for (int i = 0; i < 25; ++i) {
        const int ci = (tid >> 6) + i * 4;
        const float v = (p < INP0) ? xb[(size_t)ci * INP0 + p] : 0.f;
        t[pl][ci] = (_Float16)v;
    }
    __syncthreads();
    _Float16* xTb = xT + (size_t)b * INP0 * CIP;
    #pragma unroll
    for (int i = 0; i < 7; ++i) {
        const int idx = tid + i * 256;
        if (idx < 64 * 26) {
            const int rr = idx / 26;
            const int c  = (idx - rr * 26) * 4;
            if (p0 + rr < INP0)
                *(f16x4*)(xTb + (size_t)(p0 + rr) * CIP + c) = *(const f16x4*)&t[rr][c];
        }
    }
}

// ---------------- FUSED conv (28 taps) as MFMA GEMM, 3-deep gload_lds pipeline -------------
// gi[(b,co)][p] = bias123[co] + sum_k wp[co][k] * xT[b][p + kh*132][ci], k = kh*104+ci,
// kh in [0,28). Valid p<17424 rows never clamp (17423+27*132 = 20987 = INP0-1).
// Same 3-deep one-barrier schedule as R10's verified conv (173us @33 ksteps).
__global__ __launch_bounds__(256)
void convF(const _Float16* __restrict__ actT,   // [16][20988][104]
           const _Float16* __restrict__ wp,     // [128][KP3]
           const float*    __restrict__ bias,   // [100] (bias123)
           _Float16* __restrict__ out)          // gi [1600][GIK]
{
    constexpr int INP = INP0;
    __shared__ __align__(16) _Float16 As[3][128][32];
    __shared__ __align__(16) _Float16 Bs[3][128][32];

    const int tid  = threadIdx.x;
    const int work = xcd_remap_lin();
    const int p0   = (work % gridDim.x) * 128;
    const int b    = work / gridDim.x;
    const _Float16* act_b = actT + (size_t)b * INP * CIP;

    const int wv = tid >> 6;
    const int l  = tid & 63;
    const int ln = tid & 15;
    const int lq = (tid & 63) >> 4;
    const int rl  = l >> 2;        // lane row-local 0..15
    const int run = l & 3;         // lane 16B unit 0..3

    const _Float16* srcA0 = wp + (size_t)(wv * 16 + rl) * KP3 + run * 8;
    const _Float16* srcA1 = wp + (size_t)(64 + wv * 16 + rl) * KP3 + run * 8;
    const int plB0 = wv * 32 + rl;
    const int plB1 = wv * 32 + 16 + rl;

    f32x4 acc[7][2] = {};

    auto stage = [&](int buf, int kk) {
        const int k0 = kk * 32;
        gl16(srcA0 + k0, &As[buf][wv * 16][0]);
        gl16(srcA1 + k0, &As[buf][64 + wv * 16][0]);
        const int k   = k0 + run * 8;
        const int kh  = k / CIP;                 // 8 | 104: runs never cross kh boundary
        const int ci0 = k - kh * CIP;
        const int row0 = min(p0 + plB0 + kh * WD, INP - 1);
        const int row1 = min(p0 + plB1 + kh * WD, INP - 1);
        gl16(act_b + (size_t)row0 * CIP + ci0, &Bs[buf][wv * 32][0]);
        gl16(act_b + (size_t)row1 * CIP + ci0, &Bs[buf][wv * 32 + 16][0]);
    };

    stage(0, 0);
    stage(1, 1);
    int rb = 0;                                   // read-buffer = kk % 3
    for (int kk = 0; kk < NKC3; ++kk) {
        if (kk + 1 < NKC3) {
            asm volatile("s_waitcnt vmcnt(4) lgkmcnt(0)\n\ts_barrier" ::: "memory");
        } else {
            asm volatile("s_waitcnt vmcnt(0) lgkmcnt(0)\n\ts_barrier" ::: "memory");
        }
        if (kk + 2 < NKC3) {
            int sb = rb + 2; if (sb >= 3) sb -= 3;
            stage(sb, kk + 2);
        }
        const f16x8 bf0 = *(const f16x8*)&Bs[rb][(wv * 2 + 0) * 16 + ln][lq * 8];
        const f16x8 bf1 = *(const f16x8*)&Bs[rb][(wv * 2 + 1) * 16 + ln][lq * 8];
        #pragma unroll
        for (int mt = 0; mt < 7; ++mt) {
            const f16x8 af = *(const f16x8*)&As[rb][mt * 16 + ln][lq * 8];
            acc[mt][0] = __builtin_amdgcn_mfma_f32_16x16x32_f16(af, bf0, acc[mt][0], 0, 0, 0);
            acc[mt][1] = __builtin_amdgcn_mfma_f32_16x16x32_f16(af, bf1, acc[mt][1], 0, 0, 0);
        }
        rb = (rb + 1 == 3) ? 0 : rb + 1;
    }

    // epilogue: D row = co-within-tile (quad*4+r), col = p-within-tile (lane&15)
    #pragma unroll
    for (int j = 0; j < 2; ++j) {
        const int p = p0 + (wv * 2 + j) * 16 + ln;
        if (p >= NPF) continue;
        #pragma unroll
        for (int mt = 0; mt < 7; ++mt) {
            #pragma unroll
            for (int r = 0; r < 4; ++r) {
                const int co = mt * 16 + lq * 4 + r;
                if (co < 100)
                    out[((size_t)b * 100 + co) * GIK + p] =
                        (_Float16)(acc[mt][j][r] + bias[co]);
            }
        }
    }
}

// ---------------- big GEMM: xw += gi @ wihp^T, m-tile 128, gload_lds + dbuf ----------------
// (R9/R10 verified. A rows 1600..1663 in-bounds of the 1664-row gi alloc; guarded.)
__global__ __launch_bounds__(256)
void gemm_mfma(const _Float16* __restrict__ A,   // gi [1664][GIK]
               const _Float16* __restrict__ B,   // wihp [GIN][GIK]
               float* __restrict__ C)            // xw [1600][300]
{
    constexpr int NKG = GIK / 32;    // 545
    constexpr int SEG = 69;          // 8 z-slices
    __shared__ __align__(16) _Float16 As[2][128][32];
    __shared__ __align__(16) _Float16 Bs[2][64][32];

    const int tid  = threadIdx.x;
    const int work = xcd_remap_lin();
    const int bx   = work % 5;
    const int rem  = work / 5;
    const int by   = rem % 13;
    const int bz   = rem / 13;

    const int n0  = bx * 64;
    const int m0  = by * 128;
    const int k00 = bz * SEG;
    const int k01 = min(NKG, k00 + SEG);

    const int wv = tid >> 6, ln = tid & 15, lq = (tid & 63) >> 4;
    const int l  = tid & 63;
    const int rl = l >> 2, run = l & 3;

    const _Float16* srcA0 = A + (size_t)(m0 + wv * 32 + rl) * GIK + run * 8;
    const _Float16* srcA1 = A + (size_t)(m0 + wv * 32 + 16 + rl) * GIK + run * 8;
    const _Float16* srcB  = B + (size_t)(n0 + wv * 16 + rl) * GIK + run * 8;

    f32x4 acc[2][4] = {};

    auto stage = [&](int buf, int kk) {
        const int k0 = kk * 32;
        gl16(srcA0 + k0, &As[buf][wv * 32][0]);
        gl16(srcA1 + k0, &As[buf][wv * 32 + 16][0]);
        gl16(srcB  + k0, &Bs[buf][wv * 16][0]);
    };

    stage(0, k00);
    int cur = 0;
    for (int kk = k00; kk < k01; ++kk) {
        if (kk + 1 < k01) {
            stage(cur ^ 1, kk + 1);
            asm volatile("s_waitcnt vmcnt(3)\n\ts_barrier" ::: "memory");
        } else {
            asm volatile("s_waitcnt vmcnt(0)\n\ts_barrier" ::: "memory");
        }
        const f16x8 af0 = *(const f16x8*)&As[cur][wv * 32 + ln][lq * 8];
        const f16x8 af1 = *(const f16x8*)&As[cur][wv * 32 + 16 + ln][lq * 8];
        #pragma unroll
        for (int nt = 0; nt < 4; ++nt) {
            const f16x8 bf = *(const f16x8*)&Bs[cur][nt * 16 + ln][lq * 8];
            acc[0][nt] = __builtin_amdgcn_mfma_f32_16x16x32_f16(af0, bf, acc[0][nt], 0, 0, 0);
            acc[1][nt] = __builtin_amdgcn_mfma_f32_16x16x32_f16(af1, bf, acc[1][nt], 0, 0, 0);
        }
        asm volatile("s_waitcnt lgkmcnt(0)\n\ts_barrier" ::: "memory");
        cur ^= 1;
    }
    #pragma unroll
    for (int mt = 0; mt < 2; ++mt) {
        #pragma unroll
        for (int nt = 0; nt < 4; ++nt) {
            const int n = n0 + nt * 16 + ln;
            const int m = m0 + wv * 32 + mt * 16 + lq * 4;
            if (n < G3) {
                #pragma unroll
                for (int rr = 0; rr < 4; ++rr)
                    if (m + rr < 1600)
                        atomicAdd(&C[(size_t)(m + rr) * G3 + n], acc[mt][nt][rr]);
            }
        }
    }
}

// ---------------- xw init: xw[row, g] = b_ih[g] ----------------
__global__ __launch_bounds__(256)
void init_xw_k(const float* __restrict__ b_ih, float* __restrict__ xw)
{
    const int i = blockIdx.x * 256 + threadIdx.x;
    if (i < BTOT * TDIM * G3) xw[i] = b_ih[i % G3];
}

// ---------------- GRU scan v3: 16 blocks (one CU per batch), fp32 VALU matvec ----------------
__global__ __launch_bounds__(640)
void gru3_k(const float* __restrict__ xw, const float* __restrict__ w_hh,
            const float* __restrict__ b_hh, float* __restrict__ gout)
{
    __shared__ float h_s[128];
    __shared__ float ghp[2][304];

    const int tid  = threadIdx.x;
    const int b    = blockIdx.x;
    const int wave = tid >> 6;          // 0..9
    const int lane = tid & 63;
    const int half = (wave >= 5) ? 1 : 0;
    const int row  = (half ? wave - 5 : wave) * 64 + lane;   // 0..319
    const bool act = (row < G3);

    float wreg[50];
    #pragma unroll
    for (int j = 0; j < 50; ++j)
        wreg[j] = act ? w_hh[row * HIDN + half * 50 + j] : 0.f;
    const float bh = (act && half == 0) ? b_hh[row] : 0.f;

    if (tid < 128) h_s[tid] = 0.f;
    __syncthreads();

    const bool gate = (tid < HIDN);
    const float* xwb = xw + (size_t)b * TDIM * G3;

    float xA0 = 0.f, xA1 = 0.f, xA2 = 0.f;
    float xB0 = 0.f, xB1 = 0.f, xB2 = 0.f;
    if (gate) {
        xA0 = xwb[tid];
        xA1 = xwb[HIDN + tid];
        xA2 = xwb[2 * HIDN + tid];
    }

    auto matvec = [&]() {
        const float hlo = h_s[lane];        // full-exec snapshot (readlane hazard)
        const float hhi = h_s[64 + lane];
        float acc = bh;
        if (half == 0) {
            #pragma unroll
            for (int k = 0; k < 50; ++k)
                acc += wreg[k] * bcastf(hlo, k);
        } else {
            #pragma unroll
            for (int k = 0; k < 14; ++k)
                acc += wreg[k] * bcastf(hlo, 50 + k);
            #pragma unroll
            for (int k = 14; k < 50; ++k)
                acc += wreg[k] * bcastf(hhi, k - 14);   // global k = 50+k in [64,100)
        }
        if (act) ghp[half][row] = acc;
    };

    auto gates = [&](int t, float x0, float x1, float x2) {
        if (gate) {
            const float g0 = ghp[0][tid]            + ghp[1][tid];
            const float g1 = ghp[0][HIDN + tid]     + ghp[1][HIDN + tid];
            const float g2 = ghp[0][2 * HIDN + tid] + ghp[1][2 * HIDN + tid];
            const float hp = h_s[tid];
            const float r  = sigmoidf_(x0 + g0);
            const float z  = sigmoidf_(x1 + g1);
            const float n  = tanhf_(x2 + r * g2);
            const float hn = (1.f - z) * n + z * hp;
            h_s[tid] = hn;
            gout[((size_t)b * TDIM + t) * HIDN + tid] = hn;
        }
    };

    for (int t = 0; t < TDIM; t += 2) {
        if (gate && t + 1 < TDIM) {
            const float* p = xwb + (size_t)(t + 1) * G3;
            xB0 = p[tid]; xB1 = p[HIDN + tid]; xB2 = p[2 * HIDN + tid];
        }
        matvec();
        __syncthreads();
        gates(t, xA0, xA1, xA2);
        __syncthreads();

        if (gate && t + 2 < TDIM) {
            const float* p = xwb + (size_t)(t + 2) * G3;
            xA0 = p[tid]; xA1 = p[HIDN + tid]; xA2 = p[2 * HIDN + tid];
        }
        matvec();
        __syncthreads();
        gates(t + 1, xB0, xB1, xB2);
        __syncthreads();
    }
}

// ---------------- output heads ----------------
__global__ __launch_bounds__(256)
void heads_k(const float* __restrict__ g,
             const float* __restrict__ wy1, const float* __restrict__ by1,
             const float* __restrict__ wy2, const float* __restrict__ by2,
             float* __restrict__ out)
{
    constexpr int NY1 = BTOT * TDIM * 14;
    constexpr int NY2 = BTOT * TDIM * 3;
    const int idx = blockIdx.x * 256 + threadIdx.x;
    if (idx < NY1) {
        const int row = idx / 14, c = idx - row * 14;
        const float* gr = g + (size_t)row * HIDN;
        const float* wr = wy1 + c * HIDN;
        float acc = by1[c];
        for (int k = 0; k < HIDN; ++k) acc += gr[k] * wr[k];
        out[idx] = sigmoidf_(acc);
    } else if (idx < NY1 + NY2) {
        const int j = idx - NY1;
        const int row = j / 3, c = j - row * 3;
        const float* gr = g + (size_t)row * HIDN;
        const float* wr = wy2 + c * HIDN;
        float acc = by2[c];
        for (int k = 0; k < HIDN; ++k) acc += gr[k] * wr[k];
        out[NY1 + row * 3 + c] = tanhf(acc) * 10.f;
    }
}

// ---------------- launch ----------------
// Workspace: regA: xT (66.6 MiB) -> wihp (after convF consumes xT); gi separate (58 MiB).
extern "C" void kernel_launch(void* const* d_in, const int* in_sizes, int n_in,
                              void* d_out, int out_size, void* d_ws, size_t ws_size,
                              hipStream_t stream)
{
    (void)in_sizes; (void)n_in; (void)out_size; (void)ws_size;
    const float* x    = (const float*)d_in[0];
    const float* w1   = (const float*)d_in[1];
    const float* bc1  = (const float*)d_in[2];
    const float* w2   = (const float*)d_in[3];
    const float* bc2  = (const float*)d_in[4];
    const float* w3   = (const float*)d_in[5];
    const float* bc3  = (const float*)d_in[6];
    const float* w_ih = (const float*)d_in[7];
    const float* w_hh = (const float*)d_in[8];
    const float* b_ih = (const float*)d_in[9];
    const float* b_hh = (const float*)d_in[10];
    const float* wy1  = (const float*)d_in[11];
    const float* by1  = (const float*)d_in[12];
    const float* wy2  = (const float*)d_in[13];
    const float* by2  = (const float*)d_in[14];
    float* out = (float*)d_out;

    char* wsp = (char*)d_ws;
    auto alloc = [&](size_t bytes) -> char* {
        char* p = wsp; wsp += (bytes + 255) & ~(size_t)255; return p;
    };
    _Float16* wp3  = (_Float16*)alloc((size_t)128 * KP3 * 2);     // 745 KB
    float*    w12  = (float*)   alloc((size_t)10000 * 19 * 4);    // 760 KB
    float*    b123 = (float*)   alloc(512);
    float*    xw   = (float*)   alloc((size_t)BTOT * TDIM * G3 * 4);
    float*    g    = (float*)   alloc((size_t)BTOT * TDIM * HIDN * 4);
    _Float16* gi   = (_Float16*)alloc((size_t)1664 * GIK * 2);    // 58 MiB (gemm OOB-safe)
    char*     regA = alloc((size_t)BTOT * INP0 * CIP * 2);        // 66.6 MiB

    _Float16* xT   = (_Float16*)regA;   // [16][20988][104]
    _Float16* wihp = (_Float16*)regA;   // [320][17440] (after convF consumes xT)

    prep_w12<<<40, 256, 0, stream>>>(w1, w2, w12);
    zero_wp<<<(128 * KP3 + 255) / 256, 256, 0, stream>>>(wp3);
    prep_w123<<<40, 256, 0, stream>>>(w12, w3, wp3);
    prep_bias<<<1, 128, 0, stream>>>(w2, w3, bc1, bc2, bc3, b123);
    init_xw_k<<<(BTOT * TDIM * G3 + 255) / 256, 256, 0, stream>>>(b_ih, xw);

    transpose_x<<<dim3((INP0 + 63) / 64, BTOT), 256, 0, stream>>>(x, xT);
    convF<<<dim3(137, BTOT), 256, 0, stream>>>(xT, wp3, b123, gi);
    zero_gipad<<<100, 256, 0, stream>>>(gi);

    prep_wih<<<dim3((GIK + 255) / 256, GIN), 256, 0, stream>>>(w_ih, wihp);
    gemm_mfma<<<dim3(5, 13, 8), 256, 0, stream>>>(gi, wihp, xw);
    gru3_k<<<16, 640, 0, stream>>>(xw, w_hh, b_hh, g);
    heads_k<<<(27200 + 255) / 256, 256, 0, stream>>>(g, wy1, by1, wy2, by2, out);
}

// Round 13
// 842.449 us; speedup vs baseline: 1.2455x; 1.2455x over previous
//
#include <hip/hip_runtime.h>
#include <math.h>

// ---------------- problem constants ----------------
#define TDIM  100
#define HIDN  100
#define G3    300
#define WD    132
#define CIP   104      // padded ci pitch (multiple of 8)
#define KP    1056     // padded conv K = 10*104 -> 33 ksteps of 32
#define NKC   33
#define GIK   17440    // padded FEAT (17424 -> 545 ksteps of 32)
#define GIN   320      // padded 3*HID
#define BTOT  16
#define INP0  (159 * WD)   // 20988

typedef float    f32x4 __attribute__((ext_vector_type(4)));
typedef _Float16 f16x8 __attribute__((ext_vector_type(8)));
typedef _Float16 f16x4 __attribute__((ext_vector_type(4)));

static __device__ __forceinline__ float sigmoidf_(float x) {
    return 1.f / (1.f + __expf(-x));
}
static __device__ __forceinline__ float tanhf_(float x) {
    const float e = __expf(-2.f * fabsf(x));
    const float t = (1.f - e) / (1.f + e);
    return copysignf(t, x);
}
static __device__ __forceinline__ float bcastf(float v, int l) {
    return __int_as_float(__builtin_amdgcn_readlane(__float_as_int(v), l));
}

// async global->LDS, 16B per lane; dest = wave-uniform base + lane*16 (linear)
static __device__ __forceinline__ void gl16(const _Float16* g, _Float16* l)
{
    __builtin_amdgcn_global_load_lds(
        (const __attribute__((address_space(1))) void*)g,
        (__attribute__((address_space(3))) void*)l,
        16, 0, 0);
}

// Bijective XCD-chunked remap (m204): blocks sharing input rows -> same XCD L2.
static __device__ __forceinline__ int xcd_remap_lin()
{
    const int nwg = gridDim.x * gridDim.y * gridDim.z;
    const int lin = (blockIdx.z * gridDim.y + blockIdx.y) * gridDim.x + blockIdx.x;
    const int q = nwg >> 3, r = nwg & 7;
    const int xcd = lin & 7, idx = lin >> 3;
    return (xcd < r ? xcd * (q + 1) : r * (q + 1) + (xcd - r) * q) + idx;
}

// ---------------- weight prepack: w[co][ci][kh] -> wp[128][KP] (rows 112..127 zero) --------
__global__ __launch_bounds__(256)
void prep_convw(const float* __restrict__ w, _Float16* __restrict__ wp)
{
    const int idx = blockIdx.x * 256 + threadIdx.x;
    if (idx >= 128 * KP) return;
    const int co = idx / KP, k = idx - co * KP;
    const int kh = k / CIP, ci = k - kh * CIP;
    float v = 0.f;
    if (co < 100 && ci < 100 && kh < 10)
        v = w[(co * 100 + ci) * 10 + kh];
    wp[idx] = (_Float16)v;
}

// ---------------- w_ih prepack: [300][17424] -> [GIN][GIK] fp16, zero pad ----------------
__global__ __launch_bounds__(256)
void prep_wih(const float* __restrict__ w_ih, _Float16* __restrict__ wihp)
{
    const int k = blockIdx.x * 256 + threadIdx.x;
    const int n = blockIdx.y;
    if (k >= GIK) return;
    const float v = (n < G3 && k < 17424) ? w_ih[(size_t)n * 17424 + k] : 0.f;
    wihp[(size_t)n * GIK + k] = (_Float16)v;
}

// ---------------- x transpose: x[b][ci][p] fp32 -> xT[b][p][CIP] fp16 (pad ci zeroed) -------
__global__ __launch_bounds__(256)
void transpose_x(const float* __restrict__ x, _Float16* __restrict__ xT)
{
    __shared__ __align__(16) _Float16 t[64][116];
    const int tid = threadIdx.x;
    const int p0  = blockIdx.x * 64;
    const int b   = blockIdx.y;
    const int pl  = tid & 63;
    const int p   = p0 + pl;
    t[tid >> 2][100 + (tid & 3)] = (_Float16)0.f;   // zero the ci pad (must be finite!)
    const float* xb = x + (size_t)b * 100 * INP0;
    #pragma unroll
    for (int i = 0; i < 25; ++i) {
        const int ci = (tid >> 6) + i * 4;
        const float v = (p < INP0) ? xb[(size_t)ci * INP0 + p] : 0.f;
        t[pl][ci] = (_Float16)v;
    }
    __syncthreads();
    _Float16* xTb = xT + (size_t)b * INP0 * CIP;
    #pragma unroll
    for (int i = 0; i < 7; ++i) {
        const int idx = tid + i * 256;
        if (idx < 64 * 26) {
            const int rr = idx / 26;
            const int c  = (idx - rr * 26) * 4;
            if (p0 + rr < INP0)
                *(f16x4*)(xTb + (size_t)(p0 + rr) * CIP + c) = *(const f16x4*)&t[rr][c];
        }
    }
}

// ---------------- conv (2-phase dbuf, R9-verified) — used for conv1/conv2 ------------------
template<int HIN, bool OUTT>
__global__ __launch_bounds__(256)
void conv_mfma(const _Float16* __restrict__ actT,   // [16][HIN*132][CIP]
               const _Float16* __restrict__ wp,     // [128][KP]
               const float*    __restrict__ bias,   // [100]
               _Float16* __restrict__ out)
{
    constexpr int HOUT = HIN - 9;
    constexpr int NP   = HOUT * WD;
    constexpr int INP  = HIN * WD;

    __shared__ __align__(16) _Float16 As[2][128][32];
    __shared__ __align__(16) _Float16 Bs[2][128][32];

    const int tid  = threadIdx.x;
    const int work = xcd_remap_lin();
    const int p0   = (work % gridDim.x) * 128;
    const int b    = work / gridDim.x;
    const _Float16* act_b = actT + (size_t)b * INP * CIP;

    const int wv = tid >> 6;
    const int l  = tid & 63;
    const int ln = tid & 15;
    const int lq = (tid & 63) >> 4;
    const int rl  = l >> 2;
    const int run = l & 3;

    const _Float16* srcA0 = wp + (size_t)(wv * 16 + rl) * KP + run * 8;
    const _Float16* srcA1 = wp + (size_t)(64 + wv * 16 + rl) * KP + run * 8;
    const int plB0 = wv * 32 + rl;
    const int plB1 = wv * 32 + 16 + rl;

    f32x4 acc[7][2] = {};

    auto stage = [&](int buf, int kk) {
        const int k0 = kk * 32;
        gl16(srcA0 + k0, &As[buf][wv * 16][0]);
        gl16(srcA1 + k0, &As[buf][64 + wv * 16][0]);
        const int k   = k0 + run * 8;
        const int kh  = k / CIP;
        const int ci0 = k - kh * CIP;
        const int row0 = min(p0 + plB0 + kh * WD, INP - 1);
        const int row1 = min(p0 + plB1 + kh * WD, INP - 1);
        gl16(act_b + (size_t)row0 * CIP + ci0, &Bs[buf][wv * 32][0]);
        gl16(act_b + (size_t)row1 * CIP + ci0, &Bs[buf][wv * 32 + 16][0]);
    };

    stage(0, 0);
    int cur = 0;
    for (int kk = 0; kk < NKC; ++kk) {
        if (kk + 1 < NKC) {
            stage(cur ^ 1, kk + 1);
            asm volatile("s_waitcnt vmcnt(4)\n\ts_barrier" ::: "memory");
        } else {
            asm volatile("s_waitcnt vmcnt(0)\n\ts_barrier" ::: "memory");
        }
        const f16x8 bf0 = *(const f16x8*)&Bs[cur][(wv * 2 + 0) * 16 + ln][lq * 8];
        const f16x8 bf1 = *(const f16x8*)&Bs[cur][(wv * 2 + 1) * 16 + ln][lq * 8];
        #pragma unroll
        for (int mt = 0; mt < 7; ++mt) {
            const f16x8 af = *(const f16x8*)&As[cur][mt * 16 + ln][lq * 8];
            acc[mt][0] = __builtin_amdgcn_mfma_f32_16x16x32_f16(af, bf0, acc[mt][0], 0, 0, 0);
            acc[mt][1] = __builtin_amdgcn_mfma_f32_16x16x32_f16(af, bf1, acc[mt][1], 0, 0, 0);
        }
        asm volatile("s_waitcnt lgkmcnt(0)\n\ts_barrier" ::: "memory");
        cur ^= 1;
    }

    #pragma unroll
    for (int j = 0; j < 2; ++j) {
        const int p = p0 + (wv * 2 + j) * 16 + ln;
        if (p >= NP) continue;
        if (OUTT) {
            _Float16* orow = out + (size_t)b * NP * CIP + (size_t)p * CIP;
            #pragma unroll
            for (int mt = 0; mt < 7; ++mt) {
                const int co0 = mt * 16 + lq * 4;
                if (co0 < CIP) {
                    f16x4 v;
                    #pragma unroll
                    for (int r = 0; r < 4; ++r) {
                        const int co = co0 + r;
                        v[r] = (_Float16)(acc[mt][j][r] + (co < 100 ? bias[co] : 0.f));
                    }
                    *(f16x4*)(orow + co0) = v;
                }
            }
        } else {
            #pragma unroll
            for (int mt = 0; mt < 7; ++mt) {
                #pragma unroll
                for (int r = 0; r < 4; ++r) {
                    const int co = mt * 16 + lq * 4 + r;
                    if (co < 100)
                        out[((size_t)b * 100 + co) * GIK + p] =
                            (_Float16)(acc[mt][j][r] + bias[co]);
                }
            }
        }
    }
}

// ---------------- conv (3-deep pipeline, R10-verified: 173us) — used for conv3 -------------
template<int HIN, bool OUTT>
__global__ __launch_bounds__(256)
void conv_mfma3(const _Float16* __restrict__ actT,
                const _Float16* __restrict__ wp,
                const float*    __restrict__ bias,
                _Float16* __restrict__ out)
{
    constexpr int HOUT = HIN - 9;
    constexpr int NP   = HOUT * WD;
    constexpr int INP  = HIN * WD;

    __shared__ __align__(16) _Float16 As[3][128][32];
    __shared__ __align__(16) _Float16 Bs[3][128][32];

    const int tid  = threadIdx.x;
    const int work = xcd_remap_lin();
    const int p0   = (work % gridDim.x) * 128;
    const int b    = work / gridDim.x;
    const _Float16* act_b = actT + (size_t)b * INP * CIP;

    const int wv = tid >> 6;
    const int l  = tid & 63;
    const int ln = tid & 15;
    const int lq = (tid & 63) >> 4;
    const int rl  = l >> 2;
    const int run = l & 3;

    const _Float16* srcA0 = wp + (size_t)(wv * 16 + rl) * KP + run * 8;
    const _Float16* srcA1 = wp + (size_t)(64 + wv * 16 + rl) * KP + run * 8;
    const int plB0 = wv * 32 + rl;
    const int plB1 = wv * 32 + 16 + rl;

    f32x4 acc[7][2] = {};

    auto stage = [&](int buf, int kk) {
        const int k0 = kk * 32;
        gl16(srcA0 + k0, &As[buf][wv * 16][0]);
        gl16(srcA1 + k0, &As[buf][64 + wv * 16][0]);
        const int k   = k0 + run * 8;
        const int kh  = k / CIP;
        const int ci0 = k - kh * CIP;
        const int row0 = min(p0 + plB0 + kh * WD, INP - 1);
        const int row1 = min(p0 + plB1 + kh * WD, INP - 1);
        gl16(act_b + (size_t)row0 * CIP + ci0, &Bs[buf][wv * 32][0]);
        gl16(act_b + (size_t)row1 * CIP + ci0, &Bs[buf][wv * 32 + 16][0]);
    };

    stage(0, 0);
    stage(1, 1);
    int rb = 0;
    for (int kk = 0; kk < NKC; ++kk) {
        if (kk + 1 < NKC) {
            asm volatile("s_waitcnt vmcnt(4) lgkmcnt(0)\n\ts_barrier" ::: "memory");
        } else {
            asm volatile("s_waitcnt vmcnt(0) lgkmcnt(0)\n\ts_barrier" ::: "memory");
        }
        if (kk + 2 < NKC) {
            int sb = rb + 2; if (sb >= 3) sb -= 3;
            stage(sb, kk + 2);
        }
        const f16x8 bf0 = *(const f16x8*)&Bs[rb][(wv * 2 + 0) * 16 + ln][lq * 8];
        const f16x8 bf1 = *(const f16x8*)&Bs[rb][(wv * 2 + 1) * 16 + ln][lq * 8];
        #pragma unroll
        for (int mt = 0; mt < 7; ++mt) {
            const f16x8 af = *(const f16x8*)&As[rb][mt * 16 + ln][lq * 8];
            acc[mt][0] = __builtin_amdgcn_mfma_f32_16x16x32_f16(af, bf0, acc[mt][0], 0, 0, 0);
            acc[mt][1] = __builtin_amdgcn_mfma_f32_16x16x32_f16(af, bf1, acc[mt][1], 0, 0, 0);
        }
        rb = (rb + 1 == 3) ? 0 : rb + 1;
    }

    #pragma unroll
    for (int j = 0; j < 2; ++j) {
        const int p = p0 + (wv * 2 + j) * 16 + ln;
        if (p >= NP) continue;
        if (OUTT) {
            _Float16* orow = out + (size_t)b * NP * CIP + (size_t)p * CIP;
            #pragma unroll
            for (int mt = 0; mt < 7; ++mt) {
                const int co0 = mt * 16 + lq * 4;
                if (co0 < CIP) {
                    f16x4 v;
                    #pragma unroll
                    for (int r = 0; r < 4; ++r) {
                        const int co = co0 + r;
                        v[r] = (_Float16)(acc[mt][j][r] + (co < 100 ? bias[co] : 0.f));
                    }
                    *(f16x4*)(orow + co0) = v;
                }
            }
        } else {
            #pragma unroll
            for (int mt = 0; mt < 7; ++mt) {
                #pragma unroll
                for (int r = 0; r < 4; ++r) {
                    const int co = mt * 16 + lq * 4 + r;
                    if (co < 100)
                        out[((size_t)b * 100 + co) * GIK + p] =
                            (_Float16)(acc[mt][j][r] + bias[co]);
                }
            }
        }
    }
}

// ---------------- big GEMM: xw += gi @ wihp^T, m-tile 128 (R9-verified) --------------------
__global__ __launch_bounds__(256)
void gemm_mfma(const _Float16* __restrict__ A,   // gi [1600][GIK]
               const _Float16* __restrict__ B,   // wihp [GIN][GIK]
               float* __restrict__ C)            // xw [1600][300]
{
    constexpr int NKG = GIK / 32;    // 545
    constexpr int SEG = 69;          // 8 z-slices
    __shared__ __align__(16) _Float16 As[2][128][32];
    __shared__ __align__(16) _Float16 Bs[2][64][32];

    const int tid  = threadIdx.x;
    const int work = xcd_remap_lin();
    const int bx   = work % 5;
    const int rem  = work / 5;
    const int by   = rem % 13;
    const int bz   = rem / 13;

    const int n0  = bx * 64;
    const int m0  = by * 128;
    const int k00 = bz * SEG;
    const int k01 = min(NKG, k00 + SEG);

    const int wv = tid >> 6, ln = tid & 15, lq = (tid & 63) >> 4;
    const int l  = tid & 63;
    const int rl = l >> 2, run = l & 3;

    const _Float16* srcA0 = A + (size_t)(m0 + wv * 32 + rl) * GIK + run * 8;
    const _Float16* srcA1 = A + (size_t)(m0 + wv * 32 + 16 + rl) * GIK + run * 8;
    const _Float16* srcB  = B + (size_t)(n0 + wv * 16 + rl) * GIK + run * 8;

    f32x4 acc[2][4] = {};

    auto stage = [&](int buf, int kk) {
        const int k0 = kk * 32;
        gl16(srcA0 + k0, &As[buf][wv * 32][0]);
        gl16(srcA1 + k0, &As[buf][wv * 32 + 16][0]);
        gl16(srcB  + k0, &Bs[buf][wv * 16][0]);
    };

    stage(0, k00);
    int cur = 0;
    for (int kk = k00; kk < k01; ++kk) {
        if (kk + 1 < k01) {
            stage(cur ^ 1, kk + 1);
            asm volatile("s_waitcnt vmcnt(3)\n\ts_barrier" ::: "memory");
        } else {
            asm volatile("s_waitcnt vmcnt(0)\n\ts_barrier" ::: "memory");
        }
        const f16x8 af0 = *(const f16x8*)&As[cur][wv * 32 + ln][lq * 8];
        const f16x8 af1 = *(const f16x8*)&As[cur][wv * 32 + 16 + ln][lq * 8];
        #pragma unroll
        for (int nt = 0; nt < 4; ++nt) {
            const f16x8 bf = *(const f16x8*)&Bs[cur][nt * 16 + ln][lq * 8];
            acc[0][nt] = __builtin_amdgcn_mfma_f32_16x16x32_f16(af0, bf, acc[0][nt], 0, 0, 0);
            acc[1][nt] = __builtin_amdgcn_mfma_f32_16x16x32_f16(af1, bf, acc[1][nt], 0, 0, 0);
        }
        asm volatile("s_waitcnt lgkmcnt(0)\n\ts_barrier" ::: "memory");
        cur ^= 1;
    }
    #pragma unroll
    for (int mt = 0; mt < 2; ++mt) {
        #pragma unroll
        for (int nt = 0; nt < 4; ++nt) {
            const int n = n0 + nt * 16 + ln;
            const int m = m0 + wv * 32 + mt * 16 + lq * 4;
            if (n < G3) {
                #pragma unroll
                for (int rr = 0; rr < 4; ++rr)
                    if (m + rr < 1600)
                        atomicAdd(&C[(size_t)(m + rr) * G3 + n], acc[mt][nt][rr]);
            }
        }
    }
}

// ---------------- xw init: xw[row, g] = b_ih[g] ----------------
__global__ __launch_bounds__(256)
void init_xw_k(const float* __restrict__ b_ih, float* __restrict__ xw)
{
    const int i = blockIdx.x * 256 + threadIdx.x;
    if (i < BTOT * TDIM * G3) xw[i] = b_ih[i % G3];
}

// ---------------- GRU scan v3: 16 blocks (one CU per batch), fp32 VALU matvec ----------------
__global__ __launch_bounds__(640)
void gru3_k(const float* __restrict__ xw, const float* __restrict__ w_hh,
            const float* __restrict__ b_hh, float* __restrict__ gout)
{
    __shared__ float h_s[128];
    __shared__ float ghp[2][304];

    const int tid  = threadIdx.x;
    const int b    = blockIdx.x;
    const int wave = tid >> 6;          // 0..9
    const int lane = tid & 63;
    const int half = (wave >= 5) ? 1 : 0;
    const int row  = (half ? wave - 5 : wave) * 64 + lane;   // 0..319
    const bool act = (row < G3);

    float wreg[50];
    #pragma unroll
    for (int j = 0; j < 50; ++j)
        wreg[j] = act ? w_hh[row * HIDN + half * 50 + j] : 0.f;
    const float bh = (act && half == 0) ? b_hh[row] : 0.f;

    if (tid < 128) h_s[tid] = 0.f;
    __syncthreads();

    const bool gate = (tid < HIDN);
    const float* xwb = xw + (size_t)b * TDIM * G3;

    float xA0 = 0.f, xA1 = 0.f, xA2 = 0.f;
    float xB0 = 0.f, xB1 = 0.f, xB2 = 0.f;
    if (gate) {
        xA0 = xwb[tid];
        xA1 = xwb[HIDN + tid];
        xA2 = xwb[2 * HIDN + tid];
    }

    auto matvec = [&]() {
        const float hlo = h_s[lane];        // full-exec snapshot (readlane hazard)
        const float hhi = h_s[64 + lane];
        float acc = bh;
        if (half == 0) {
            #pragma unroll
            for (int k = 0; k < 50; ++k)
                acc += wreg[k] * bcastf(hlo, k);
        } else {
            #pragma unroll
            for (int k = 0; k < 14; ++k)
                acc += wreg[k] * bcastf(hlo, 50 + k);
            #pragma unroll
            for (int k = 14; k < 50; ++k)
                acc += wreg[k] * bcastf(hhi, k - 14);   // global k = 50+k in [64,100)
        }
        if (act) ghp[half][row] = acc;
    };

    auto gates = [&](int t, float x0, float x1, float x2) {
        if (gate) {
            const float g0 = ghp[0][tid]            + ghp[1][tid];
            const float g1 = ghp[0][HIDN + tid]     + ghp[1][HIDN + tid];
            const float g2 = ghp[0][2 * HIDN + tid] + ghp[1][2 * HIDN + tid];
            const float hp = h_s[tid];
            const float r  = sigmoidf_(x0 + g0);
            const float z  = sigmoidf_(x1 + g1);
            const float n  = tanhf_(x2 + r * g2);
            const float hn = (1.f - z) * n + z * hp;
            h_s[tid] = hn;
            gout[((size_t)b * TDIM + t) * HIDN + tid] = hn;
        }
    };

    for (int t = 0; t < TDIM; t += 2) {
        if (gate && t + 1 < TDIM) {
            const float* p = xwb + (size_t)(t + 1) * G3;
            xB0 = p[tid]; xB1 = p[HIDN + tid]; xB2 = p[2 * HIDN + tid];
        }
        matvec();
        __syncthreads();
        gates(t, xA0, xA1, xA2);
        __syncthreads();

        if (gate && t + 2 < TDIM) {
            const float* p = xwb + (size_t)(t + 2) * G3;
            xA0 = p[tid]; xA1 = p[HIDN + tid]; xA2 = p[2 * HIDN + tid];
        }
        matvec();
        __syncthreads();
        gates(t + 1, xB0, xB1, xB2);
        __syncthreads();
    }
}

// ---------------- output heads ----------------
__global__ __launch_bounds__(256)
void heads_k(const float* __restrict__ g,
             const float* __restrict__ wy1, const float* __restrict__ by1,
             const float* __restrict__ wy2, const float* __restrict__ by2,
             float* __restrict__ out)
{
    constexpr int NY1 = BTOT * TDIM * 14;
    constexpr int NY2 = BTOT * TDIM * 3;
    const int idx = blockIdx.x * 256 + threadIdx.x;
    if (idx < NY1) {
        const int row = idx / 14, c = idx - row * 14;
        const float* gr = g + (size_t)row * HIDN;
        const float* wr = wy1 + c * HIDN;
        float acc = by1[c];
        for (int k = 0; k < HIDN; ++k) acc += gr[k] * wr[k];
        out[idx] = sigmoidf_(acc);
    } else if (idx < NY1 + NY2) {
        const int j = idx - NY1;
        const int row = j / 3, c = j - row * 3;
        const float* gr = g + (size_t)row * HIDN;
        const float* wr = wy2 + c * HIDN;
        float acc = by2[c];
        for (int k = 0; k < HIDN; ++k) acc += gr[k] * wr[k];
        out[NY1 + row * 3 + c] = tanhf(acc) * 10.f;
    }
}

// ---------------- launch ----------------
// Workspace: region A: xT -> c2T -> wihp ; region B: c1T -> gi (aliased, ~133 MiB)
extern "C" void kernel_launch(void* const* d_in, const int* in_sizes, int n_in,
                              void* d_out, int out_size, void* d_ws, size_t ws_size,
                              hipStream_t stream)
{
    (void)in_sizes; (void)n_in; (void)out_size; (void)ws_size;
    const float* x    = (const float*)d_in[0];
    const float* w1   = (const float*)d_in[1];
    const float* bc1  = (const float*)d_in[2];
    const float* w2   = (const float*)d_in[3];
    const float* bc2  = (const float*)d_in[4];
    const float* w3   = (const float*)d_in[5];
    const float* bc3  = (const float*)d_in[6];
    const float* w_ih = (const float*)d_in[7];
    const float* w_hh = (const float*)d_in[8];
    const float* b_ih = (const float*)d_in[9];
    const float* b_hh = (const float*)d_in[10];
    const float* wy1  = (const float*)d_in[11];
    const float* by1  = (const float*)d_in[12];
    const float* wy2  = (const float*)d_in[13];
    const float* by2  = (const float*)d_in[14];
    float* out = (float*)d_out;

    char* wsp = (char*)d_ws;
    auto alloc = [&](size_t bytes) -> char* {
        char* p = wsp; wsp += (bytes + 255) & ~(size_t)255; return p;
    };
    _Float16* wp1  = (_Float16*)alloc((size_t)128 * KP * 2);
    _Float16* wp2  = (_Float16*)alloc((size_t)128 * KP * 2);
    _Float16* wp3  = (_Float16*)alloc((size_t)128 * KP * 2);
    float*    xw   = (float*)   alloc((size_t)BTOT * TDIM * G3 * 4);
    float*    g    = (float*)   alloc((size_t)BTOT * TDIM * HIDN * 4);
    char*     regA = alloc((size_t)BTOT * INP0 * CIP * 2);        // 66.6 MiB
    char*     regB = alloc((size_t)BTOT * 150 * WD * CIP * 2);    // 62.8 MiB

    _Float16* xT   = (_Float16*)regA;   // [16][20988][104]
    _Float16* c2T  = (_Float16*)regA;   // [16][18612][104] (after xT dead)
    _Float16* wihp = (_Float16*)regA;   // [320][17440]     (after c2T dead)
    _Float16* c1T  = (_Float16*)regB;   // [16][19800][104]
    _Float16* gi   = (_Float16*)regB;   // [1600][17440]    (after c1T dead)

    prep_convw<<<(128 * KP + 255) / 256, 256, 0, stream>>>(w1, wp1);
    prep_convw<<<(128 * KP + 255) / 256, 256, 0, stream>>>(w2, wp2);
    prep_convw<<<(128 * KP + 255) / 256, 256, 0, stream>>>(w3, wp3);
    init_xw_k<<<(BTOT * TDIM * G3 + 255) / 256, 256, 0, stream>>>(b_ih, xw);

    transpose_x<<<dim3((INP0 + 63) / 64, BTOT), 256, 0, stream>>>(x, xT);
    conv_mfma <159, true ><<<dim3(155, BTOT), 256, 0, stream>>>(xT,  wp1, bc1, c1T);
    conv_mfma <150, true ><<<dim3(146, BTOT), 256, 0, stream>>>(c1T, wp2, bc2, c2T);
    conv_mfma3<141, false><<<dim3(137, BTOT), 256, 0, stream>>>(c2T, wp3, bc3, gi);

    prep_wih<<<dim3((GIK + 255) / 256, GIN), 256, 0, stream>>>(w_ih, wihp);
    gemm_mfma<<<dim3(5, 13, 8), 256, 0, stream>>>(gi, wihp, xw);
    gru3_k<<<16, 640, 0, stream>>>(xw, w_hh, b_hh, g);
    heads_k<<<(27200 + 255) / 256, 256, 0, stream>>>(g, wy1, by1, wy2, by2, out);
}